// Round 3
// baseline (149.982 us; speedup 1.0000x reference)
//
#include <hip/hip_runtime.h>
#include <math.h>

#define C_NUM 80
#define B_NUM 16
#define T_NUM 256
#define EPSF  1e-7f

#define NSLOT 134400            // 16*(6400+1600+400) valid anchors across scales
#define WS_NEEDED (64 + NSLOT*4 + 4*NSLOT*4)

__device__ __forceinline__ float softplusf(float z) {
    return fmaxf(z, 0.0f) + log1pf(expf(-fabsf(z)));
}

__device__ __forceinline__ void tile_decode(int tile, int& s, int& b, int& chunk,
                                            int& H, float& stride, int& sbase) {
    if (tile < 400)      { s = 0; b = tile / 25;             chunk = tile % 25; H = 80; stride =  8.f; sbase = 0; }
    else if (tile < 512) { int r = tile - 400; s = 1; b = r / 7; chunk = r % 7; H = 40; stride = 16.f; sbase = 102400; }
    else                 { int r = tile - 512; s = 2; b = r / 2; chunk = r % 2; H = 20; stride = 32.f; sbase = 128000; }
}

__global__ __launch_bounds__(64)
void yolo_init(float* __restrict__ acc) {
    if (threadIdx.x < 12) acc[threadIdx.x] = 0.0f;
}

// ---------------- Kernel A: decode + IoU match + CIoU + box/npos ----------------
__global__ __launch_bounds__(256)
void yolo_match(const float* __restrict__ reg0, const float* __restrict__ reg1,
                const float* __restrict__ reg2,
                const float* __restrict__ tboxes, const int* __restrict__ t_batch,
                const int* __restrict__ t_cls, float* __restrict__ acc,
                int* __restrict__ btc)
{
    __shared__ float s_x1[T_NUM], s_y1[T_NUM], s_x2[T_NUM], s_y2[T_NUM], s_ar[T_NUM];
    __shared__ int   s_tc[T_NUM];
    __shared__ int   s_list[T_NUM];
    __shared__ int   s_wcnt[4];
    __shared__ float s_red[4][2];

    const int tid = threadIdx.x;
    int s, b, chunk, H, sbase; float stride;
    tile_decode(blockIdx.x, s, b, chunk, H, stride, sbase);
    const int A = H * H;
    const float* regp = (s == 0) ? reg0 : (s == 1) ? reg1 : reg2;

    {
        float4 t4 = reinterpret_cast<const float4*>(tboxes)[tid];
        s_x1[tid] = t4.x; s_y1[tid] = t4.y; s_x2[tid] = t4.z; s_y2[tid] = t4.w;
        s_ar[tid] = (t4.z - t4.x) * (t4.w - t4.y);
        s_tc[tid] = t_cls[tid];
    }
    const int lane = tid & 63, wave = tid >> 6;
    int match = (t_batch[tid] == b) ? 1 : 0;
    unsigned long long mask = __ballot(match != 0);
    if (lane == 0) s_wcnt[wave] = __popcll(mask);
    __syncthreads();
    int base = 0;
    #pragma unroll
    for (int w = 0; w < 4; ++w) if (w < wave) base += s_wcnt[w];
    const int nT = s_wcnt[0] + s_wcnt[1] + s_wcnt[2] + s_wcnt[3];
    if (match) {
        int pfx = __popcll(mask & (((unsigned long long)1 << lane) - 1ull));
        s_list[base + pfx] = tid;
    }
    __syncthreads();

    const int a = chunk * 256 + tid;
    float cnt = 0.f, boxs = 0.f;
    if (a < A) {
        const float* rp = regp + (b * 4) * A + a;
        float rx = rp[0], ry = rp[A], rw = rp[2 * A], rh = rp[3 * A];
        float gx = (float)(a % H), gy = (float)(a / H);
        float x = (1.f / (1.f + expf(-rx)) + gx) * stride;
        float y = (1.f / (1.f + expf(-ry)) + gy) * stride;
        float w = expf(rw) * stride;
        float h = expf(rh) * stride;
        float px1 = x - 0.5f * w, py1 = y - 0.5f * h;
        float px2 = x + 0.5f * w, py2 = y + 0.5f * h;
        float pw = px2 - px1, ph = py2 - py1;
        float parea = pw * ph;

        float maxiou = -1.f; int best = 0;
        for (int j = 0; j < nT; ++j) {
            int t = s_list[j];
            float ix = fminf(px2, s_x2[t]) - fmaxf(px1, s_x1[t]);
            float iy = fminf(py2, s_y2[t]) - fmaxf(py1, s_y1[t]);
            float inter = fmaxf(ix, 0.f) * fmaxf(iy, 0.f);
            float iou = inter / (parea + s_ar[t] - inter + EPSF);
            if (iou > maxiou) { maxiou = iou; best = t; }
        }
        const bool pos = maxiou > 0.5f;
        btc[sbase + b * A + a] = pos ? s_tc[best] : -1;

        if (pos) {
            cnt = 1.f;
            float gx1 = s_x1[best], gy1 = s_y1[best], gx2 = s_x2[best], gy2 = s_y2[best];
            float gw = gx2 - gx1, gh = gy2 - gy1;
            float ix = fminf(px2, gx2) - fmaxf(px1, gx1);
            float iy = fminf(py2, gy2) - fmaxf(py1, gy1);
            float inter = fmaxf(ix, 0.f) * fmaxf(iy, 0.f);
            float uni = parea + gw * gh - inter + EPSF;
            float iou = inter / uni;
            float cw = fmaxf(px2, gx2) - fminf(px1, gx1);
            float ch = fmaxf(py2, gy2) - fminf(py1, gy1);
            float c2 = cw * cw + ch * ch + EPSF;
            float dx = 0.5f * ((px1 + px2) - (gx1 + gx2));
            float dy = 0.5f * ((py1 + py2) - (gy1 + gy2));
            float rho2 = dx * dx + dy * dy;
            float dv = atanf(gw / (gh + EPSF)) - atanf(pw / (ph + EPSF));
            float v = 0.40528473456935108577f * dv * dv;
            float alpha = v / (v - iou + 1.f + EPSF);
            boxs = 1.f - (iou - rho2 / c2 - alpha * v);
        }
    }

    #pragma unroll
    for (int off = 32; off > 0; off >>= 1) {
        cnt  += __shfl_down(cnt,  off, 64);
        boxs += __shfl_down(boxs, off, 64);
    }
    if (lane == 0) { s_red[wave][0] = cnt; s_red[wave][1] = boxs; }
    __syncthreads();
    if (tid == 0) {
        float rc = 0.f, rb = 0.f;
        #pragma unroll
        for (int w = 0; w < 4; ++w) { rc += s_red[w][0]; rb += s_red[w][1]; }
        atomicAdd(&acc[s * 4 + 0], rc);
        atomicAdd(&acc[s * 4 + 1], rb);
    }
}

// ---------------- Kernel B: class pass (the 43MB stream), classes split 4x20 ----------------
// bid = tile*4 + chunk4. Wave w covers classes 20*chunk4 + [5w,5w+5);
// lane covers tile anchors 4*lane..4*lane+3 (float4).
__global__ __launch_bounds__(256)
void yolo_cls(const float* __restrict__ cls0, const float* __restrict__ cls1,
              const float* __restrict__ cls2,
              const int* __restrict__ btc, float* __restrict__ pmax,
              float* __restrict__ acc)
{
    __shared__ float4 s_pmax[4][64];
    __shared__ float  s_red[4];

    const int tid = threadIdx.x;
    const int lane = tid & 63, wave = tid >> 6;
    const int tile = blockIdx.x >> 2, chunk4 = blockIdx.x & 3;

    int s, b, chunk, H, sbase; float stride;
    tile_decode(tile, s, b, chunk, H, stride, sbase);
    const int A = H * H;
    const float* clsp = (s == 0) ? cls0 : (s == 1) ? cls1 : cls2;

    const int ta0 = 4 * lane;
    const int a0  = chunk * 256 + ta0;
    const bool valid = (a0 < A);                  // A%4==0 -> all-or-nothing per lane
    const int c0 = 20 * chunk4 + 5 * wave;
    const float* cw = clsp + ((size_t)(b * C_NUM + c0)) * A + (valid ? a0 : 0);
    const int slot0 = sbase + b * A + (valid ? a0 : 0);

    // 5 independent float4 loads (keep them all in flight)
    float4 z0 = *reinterpret_cast<const float4*>(cw);
    float4 z1 = *reinterpret_cast<const float4*>(cw + (size_t)A);
    float4 z2 = *reinterpret_cast<const float4*>(cw + (size_t)2 * A);
    float4 z3 = *reinterpret_cast<const float4*>(cw + (size_t)3 * A);
    float4 z4 = *reinterpret_cast<const float4*>(cw + (size_t)4 * A);

    float4 mx;
    mx.x = fmaxf(fmaxf(fmaxf(z0.x, z1.x), fmaxf(z2.x, z3.x)), z4.x);
    mx.y = fmaxf(fmaxf(fmaxf(z0.y, z1.y), fmaxf(z2.y, z3.y)), z4.y);
    mx.z = fmaxf(fmaxf(fmaxf(z0.z, z1.z), fmaxf(z2.z, z3.z)), z4.z);
    mx.w = fmaxf(fmaxf(fmaxf(z0.w, z1.w), fmaxf(z2.w, z3.w)), z4.w);
    s_pmax[wave][lane] = mx;

    // cls-BCE partial (linear across chunks -> atomic). pos iff btc >= 0.
    float clss = 0.f;
    if (valid) {
        int4 t4 = *reinterpret_cast<const int4*>(btc + slot0);
        if ((t4.x >= 0) | (t4.y >= 0) | (t4.z >= 0) | (t4.w >= 0)) {
            const float4 zz[5] = { z0, z1, z2, z3, z4 };
            #pragma unroll
            for (int cl = 0; cl < 5; ++cl) {
                const int cg = c0 + cl;
                if (t4.x >= 0) { clss += softplusf(zz[cl].x); if (cg == t4.x) clss -= zz[cl].x; }
                if (t4.y >= 0) { clss += softplusf(zz[cl].y); if (cg == t4.y) clss -= zz[cl].y; }
                if (t4.z >= 0) { clss += softplusf(zz[cl].z); if (cg == t4.z) clss -= zz[cl].z; }
                if (t4.w >= 0) { clss += softplusf(zz[cl].w); if (cg == t4.w) clss -= zz[cl].w; }
            }
        }
    }
    #pragma unroll
    for (int off = 32; off > 0; off >>= 1) clss += __shfl_down(clss, off, 64);
    if (lane == 0) s_red[wave] = clss;
    __syncthreads();
    if (tid == 0) {
        float r = s_red[0] + s_red[1] + s_red[2] + s_red[3];
        atomicAdd(&acc[s * 4 + 2], r);
    }

    // owner thread `tid` combines the 4 wave-partials for tile-anchor `tid`
    const int a = chunk * 256 + tid;
    if (a < A) {
        const float* p0 = reinterpret_cast<const float*>(s_pmax[0]);
        const float* p1 = reinterpret_cast<const float*>(s_pmax[1]);
        const float* p2 = reinterpret_cast<const float*>(s_pmax[2]);
        const float* p3 = reinterpret_cast<const float*>(s_pmax[3]);
        float m = fmaxf(fmaxf(p0[tid], p1[tid]), fmaxf(p2[tid], p3[tid]));
        pmax[(size_t)chunk4 * NSLOT + sbase + b * A + a] = m;
    }
}

// ---------------- Kernel C: obj loss from the 4 max planes ----------------
__global__ __launch_bounds__(256)
void yolo_obj(const int* __restrict__ btc, const float* __restrict__ pmax,
              float* __restrict__ acc)
{
    __shared__ float s_red[4];
    const int tid = threadIdx.x;
    const int lane = tid & 63, wave = tid >> 6;
    const int slot = blockIdx.x * 256 + tid;          // 525*256 == NSLOT exactly
    const int s = (blockIdx.x < 400) ? 0 : (blockIdx.x < 500) ? 1 : 2;

    float m = fmaxf(fmaxf(pmax[slot], pmax[NSLOT + slot]),
                    fmaxf(pmax[2 * NSLOT + slot], pmax[3 * NSLOT + slot]));
    bool pos = btc[slot] >= 0;
    float objs = softplusf(m) - (pos ? m : 0.f);

    #pragma unroll
    for (int off = 32; off > 0; off >>= 1) objs += __shfl_down(objs, off, 64);
    if (lane == 0) s_red[wave] = objs;
    __syncthreads();
    if (tid == 0) atomicAdd(&acc[s * 4 + 3], s_red[0] + s_red[1] + s_red[2] + s_red[3]);
}

__global__ __launch_bounds__(64)
void yolo_finalize(const float* __restrict__ acc, float* __restrict__ out) {
    if (threadIdx.x == 0) {
        const float inv_anchors[3] = { 1.f / (16.f * 6400.f), 1.f / (16.f * 1600.f), 1.f / (16.f * 400.f) };
        float total = 0.f;
        #pragma unroll
        for (int s = 0; s < 3; ++s) {
            float npos = fmaxf(acc[s * 4 + 0], 1.f);
            total += 7.5f * acc[s * 4 + 1] / npos
                   + 0.5f * acc[s * 4 + 2] / (npos * (float)C_NUM)
                   + acc[s * 4 + 3] * inv_anchors[s];
        }
        out[0] = total;
    }
}

// ---------------- Fallback monolithic kernel (if ws too small) ----------------
__global__ __launch_bounds__(256)
void yolo_mono(const float* __restrict__ cls0, const float* __restrict__ reg0,
               const float* __restrict__ cls1, const float* __restrict__ reg1,
               const float* __restrict__ cls2, const float* __restrict__ reg2,
               const float* __restrict__ tboxes, const int* __restrict__ t_batch,
               const int* __restrict__ t_cls, float* __restrict__ acc)
{
    __shared__ float s_x1[T_NUM], s_y1[T_NUM], s_x2[T_NUM], s_y2[T_NUM], s_ar[T_NUM];
    __shared__ int   s_tc[T_NUM];
    __shared__ int   s_list[T_NUM];
    __shared__ int   s_wcnt[4];
    __shared__ float4 s_pmax[4][64];
    __shared__ float4 s_psum[4][64];
    __shared__ int   s_pos[256];
    __shared__ int   s_btc[256];
    __shared__ float s_red[4][4];

    const int tid = threadIdx.x;
    int s, b, chunk, H, sbase; float stride;
    tile_decode(blockIdx.x, s, b, chunk, H, stride, sbase);
    const int A = H * H;
    const float* clsp = (s == 0) ? cls0 : (s == 1) ? cls1 : cls2;
    const float* regp = (s == 0) ? reg0 : (s == 1) ? reg1 : reg2;

    {
        float4 t4 = reinterpret_cast<const float4*>(tboxes)[tid];
        s_x1[tid] = t4.x; s_y1[tid] = t4.y; s_x2[tid] = t4.z; s_y2[tid] = t4.w;
        s_ar[tid] = (t4.z - t4.x) * (t4.w - t4.y);
        s_tc[tid] = t_cls[tid];
    }
    const int lane = tid & 63, wave = tid >> 6;
    int match = (t_batch[tid] == b) ? 1 : 0;
    unsigned long long mask = __ballot(match != 0);
    if (lane == 0) s_wcnt[wave] = __popcll(mask);
    __syncthreads();
    int base = 0;
    #pragma unroll
    for (int w = 0; w < 4; ++w) if (w < wave) base += s_wcnt[w];
    const int nT = s_wcnt[0] + s_wcnt[1] + s_wcnt[2] + s_wcnt[3];
    if (match) {
        int pfx = __popcll(mask & (((unsigned long long)1 << lane) - 1ull));
        s_list[base + pfx] = tid;
    }
    __syncthreads();

    const int a = chunk * 256 + tid;
    float cnt = 0.f, boxs = 0.f, clss = 0.f, objs = 0.f;
    bool pos = false;
    if (a < A) {
        const float* rp = regp + (b * 4) * A + a;
        float rx = rp[0], ry = rp[A], rw = rp[2 * A], rh = rp[3 * A];
        float gx = (float)(a % H), gy = (float)(a / H);
        float x = (1.f / (1.f + expf(-rx)) + gx) * stride;
        float y = (1.f / (1.f + expf(-ry)) + gy) * stride;
        float w = expf(rw) * stride;
        float h = expf(rh) * stride;
        float px1 = x - 0.5f * w, py1 = y - 0.5f * h;
        float px2 = x + 0.5f * w, py2 = y + 0.5f * h;
        float pw = px2 - px1, ph = py2 - py1;
        float parea = pw * ph;
        float maxiou = -1.f; int best = 0;
        for (int j = 0; j < nT; ++j) {
            int t = s_list[j];
            float ix = fminf(px2, s_x2[t]) - fmaxf(px1, s_x1[t]);
            float iy = fminf(py2, s_y2[t]) - fmaxf(py1, s_y1[t]);
            float inter = fmaxf(ix, 0.f) * fmaxf(iy, 0.f);
            float iou = inter / (parea + s_ar[t] - inter + EPSF);
            if (iou > maxiou) { maxiou = iou; best = t; }
        }
        pos = maxiou > 0.5f;
        s_pos[tid] = pos ? 1 : 0;
        s_btc[tid] = s_tc[best];
        if (pos) {
            cnt = 1.f;
            float gx1 = s_x1[best], gy1 = s_y1[best], gx2 = s_x2[best], gy2 = s_y2[best];
            float gw = gx2 - gx1, gh = gy2 - gy1;
            float ix = fminf(px2, gx2) - fmaxf(px1, gx1);
            float iy = fminf(py2, gy2) - fmaxf(py1, gy1);
            float inter = fmaxf(ix, 0.f) * fmaxf(iy, 0.f);
            float uni = parea + gw * gh - inter + EPSF;
            float iou = inter / uni;
            float cw = fmaxf(px2, gx2) - fminf(px1, gx1);
            float ch = fmaxf(py2, gy2) - fminf(py1, gy1);
            float c2 = cw * cw + ch * ch + EPSF;
            float dx = 0.5f * ((px1 + px2) - (gx1 + gx2));
            float dy = 0.5f * ((py1 + py2) - (gy1 + gy2));
            float rho2 = dx * dx + dy * dy;
            float dv = atanf(gw / (gh + EPSF)) - atanf(pw / (ph + EPSF));
            float v = 0.40528473456935108577f * dv * dv;
            float alpha = v / (v - iou + 1.f + EPSF);
            boxs = 1.f - (iou - rho2 / c2 - alpha * v);
        }
    } else { s_pos[tid] = 0; s_btc[tid] = 0; }
    __syncthreads();
    {
        const int ta0 = 4 * lane;
        const int a0  = chunk * 256 + ta0;
        const bool av = (a0 < A);
        const float* cw = clsp + ((size_t)(b * C_NUM + 20 * wave)) * A + (av ? a0 : 0);
        float4 mx = make_float4(-INFINITY, -INFINITY, -INFINITY, -INFINITY);
        #pragma unroll
        for (int cl = 0; cl < 20; ++cl) {
            float4 z = *reinterpret_cast<const float4*>(cw + (size_t)cl * A);
            mx.x = fmaxf(mx.x, z.x); mx.y = fmaxf(mx.y, z.y);
            mx.z = fmaxf(mx.z, z.z); mx.w = fmaxf(mx.w, z.w);
        }
        s_pmax[wave][lane] = mx;
        const int p0 = s_pos[ta0], p1 = s_pos[ta0+1], p2 = s_pos[ta0+2], p3 = s_pos[ta0+3];
        float4 sm = make_float4(0.f, 0.f, 0.f, 0.f);
        if (p0 | p1 | p2 | p3) {
            const int t0 = s_btc[ta0], t1 = s_btc[ta0+1], t2 = s_btc[ta0+2], t3 = s_btc[ta0+3];
            #pragma unroll 4
            for (int cl = 0; cl < 20; ++cl) {
                const int cg = 20 * wave + cl;
                float4 z = *reinterpret_cast<const float4*>(cw + (size_t)cl * A);
                if (p0) { sm.x += softplusf(z.x); if (cg == t0) sm.x -= z.x; }
                if (p1) { sm.y += softplusf(z.y); if (cg == t1) sm.y -= z.y; }
                if (p2) { sm.z += softplusf(z.z); if (cg == t2) sm.z -= z.z; }
                if (p3) { sm.w += softplusf(z.w); if (cg == t3) sm.w -= z.w; }
            }
        }
        s_psum[wave][lane] = sm;
    }
    __syncthreads();
    if (a < A) {
        float m = fmaxf(fmaxf(reinterpret_cast<const float*>(s_pmax[0])[tid],
                              reinterpret_cast<const float*>(s_pmax[1])[tid]),
                        fmaxf(reinterpret_cast<const float*>(s_pmax[2])[tid],
                              reinterpret_cast<const float*>(s_pmax[3])[tid]));
        objs = softplusf(m) - (pos ? m : 0.f);
        if (pos) {
            clss = reinterpret_cast<const float*>(s_psum[0])[tid]
                 + reinterpret_cast<const float*>(s_psum[1])[tid]
                 + reinterpret_cast<const float*>(s_psum[2])[tid]
                 + reinterpret_cast<const float*>(s_psum[3])[tid];
        }
    }
    #pragma unroll
    for (int off = 32; off > 0; off >>= 1) {
        cnt  += __shfl_down(cnt,  off, 64);
        boxs += __shfl_down(boxs, off, 64);
        clss += __shfl_down(clss, off, 64);
        objs += __shfl_down(objs, off, 64);
    }
    if (lane == 0) {
        s_red[wave][0] = cnt;  s_red[wave][1] = boxs;
        s_red[wave][2] = clss; s_red[wave][3] = objs;
    }
    __syncthreads();
    if (tid == 0) {
        float rc = 0.f, rb = 0.f, rl = 0.f, ro = 0.f;
        #pragma unroll
        for (int w = 0; w < 4; ++w) {
            rc += s_red[w][0]; rb += s_red[w][1];
            rl += s_red[w][2]; ro += s_red[w][3];
        }
        atomicAdd(&acc[s * 4 + 0], rc);
        atomicAdd(&acc[s * 4 + 1], rb);
        atomicAdd(&acc[s * 4 + 2], rl);
        atomicAdd(&acc[s * 4 + 3], ro);
    }
}

extern "C" void kernel_launch(void* const* d_in, const int* in_sizes, int n_in,
                              void* d_out, int out_size, void* d_ws, size_t ws_size,
                              hipStream_t stream) {
    const float *cls[3] = {nullptr, nullptr, nullptr};
    const float *reg[3] = {nullptr, nullptr, nullptr};
    const float *tboxes = nullptr;
    const int *t_batch = nullptr, *t_cls = nullptr;
    for (int i = 0; i < n_in; ++i) {
        switch (in_sizes[i]) {
            case 16 * 80 * 6400: cls[0] = (const float*)d_in[i]; break;
            case 16 * 80 * 1600: cls[1] = (const float*)d_in[i]; break;
            case 16 * 80 * 400:  cls[2] = (const float*)d_in[i]; break;
            case 16 * 4 * 6400:  reg[0] = (const float*)d_in[i]; break;
            case 16 * 4 * 1600:  reg[1] = (const float*)d_in[i]; break;
            case 16 * 4 * 400:   reg[2] = (const float*)d_in[i]; break;
            case 256 * 4:        tboxes = (const float*)d_in[i]; break;
            case 256:
                if (!t_batch) t_batch = (const int*)d_in[i];
                else          t_cls   = (const int*)d_in[i];
                break;
            default: break;
        }
    }
    float* acc  = (float*)d_ws;                          // 12 f32 (+pad to 64B)
    int*   btc  = (int*)((char*)d_ws + 64);              // NSLOT ints
    float* pmax = (float*)((char*)d_ws + 64 + NSLOT * 4);// 4*NSLOT floats
    float* out  = (float*)d_out;

    hipLaunchKernelGGL(yolo_init, dim3(1), dim3(64), 0, stream, acc);
    if (ws_size >= (size_t)WS_NEEDED) {
        hipLaunchKernelGGL(yolo_match, dim3(544), dim3(256), 0, stream,
                           reg[0], reg[1], reg[2], tboxes, t_batch, t_cls, acc, btc);
        hipLaunchKernelGGL(yolo_cls, dim3(2176), dim3(256), 0, stream,
                           cls[0], cls[1], cls[2], btc, pmax, acc);
        hipLaunchKernelGGL(yolo_obj, dim3(525), dim3(256), 0, stream, btc, pmax, acc);
    } else {
        hipLaunchKernelGGL(yolo_mono, dim3(544), dim3(256), 0, stream,
                           cls[0], reg[0], cls[1], reg[1], cls[2], reg[2],
                           tboxes, t_batch, t_cls, acc);
    }
    hipLaunchKernelGGL(yolo_finalize, dim3(1), dim3(64), 0, stream, acc, out);
}

// Round 4
// 115.951 us; speedup vs baseline: 1.2935x; 1.2935x over previous
//
#include <hip/hip_runtime.h>
#include <math.h>

#define C_NUM 80
#define T_NUM 256
#define EPSF  1e-7f

#define NSLOT 134400            // 16*(6400+1600+400) anchors across scales
// ws layout (all written before read every call; no pre-zero needed)
#define P1_OFF 537600           // 544 float2 {npos, box} per match block
#define P2_OFF 541952           // 2100 float2 {cls, obj} per clsobj block
#define WS_NEEDED (P2_OFF + 2100 * 8)

__device__ __forceinline__ float softplusf(float z) {
    return fmaxf(z, 0.0f) + log1pf(expf(-fabsf(z)));
}

__device__ __forceinline__ void tile_decode(int tile, int& s, int& b, int& chunk,
                                            int& H, float& stride, int& sbase) {
    if (tile < 400)      { s = 0; b = tile / 25;             chunk = tile % 25; H = 80; stride =  8.f; sbase = 0; }
    else if (tile < 512) { int r = tile - 400; s = 1; b = r / 7; chunk = r % 7; H = 40; stride = 16.f; sbase = 102400; }
    else                 { int r = tile - 512; s = 2; b = r / 2; chunk = r % 2; H = 20; stride = 32.f; sbase = 128000; }
}

// ---------------- K1: decode + IoU match + CIoU; per-block partials, no atomics ----------------
__global__ __launch_bounds__(256)
void yolo_match(const float* __restrict__ reg0, const float* __restrict__ reg1,
                const float* __restrict__ reg2,
                const float* __restrict__ tboxes, const int* __restrict__ t_batch,
                const int* __restrict__ t_cls,
                int* __restrict__ btc, float2* __restrict__ p1)
{
    __shared__ float s_x1[T_NUM], s_y1[T_NUM], s_x2[T_NUM], s_y2[T_NUM], s_ar[T_NUM];
    __shared__ int   s_tc[T_NUM];
    __shared__ int   s_list[T_NUM];
    __shared__ int   s_wcnt[4];
    __shared__ float s_red[4][2];

    const int tid = threadIdx.x;
    int s, b, chunk, H, sbase; float stride;
    tile_decode(blockIdx.x, s, b, chunk, H, stride, sbase);
    const int A = H * H;
    const float* regp = (s == 0) ? reg0 : (s == 1) ? reg1 : reg2;

    {
        float4 t4 = reinterpret_cast<const float4*>(tboxes)[tid];
        s_x1[tid] = t4.x; s_y1[tid] = t4.y; s_x2[tid] = t4.z; s_y2[tid] = t4.w;
        s_ar[tid] = (t4.z - t4.x) * (t4.w - t4.y);
        s_tc[tid] = t_cls[tid];
    }
    const int lane = tid & 63, wave = tid >> 6;
    int match = (t_batch[tid] == b) ? 1 : 0;
    unsigned long long mask = __ballot(match != 0);
    if (lane == 0) s_wcnt[wave] = __popcll(mask);
    __syncthreads();
    int base = 0;
    #pragma unroll
    for (int w = 0; w < 4; ++w) if (w < wave) base += s_wcnt[w];
    const int nT = s_wcnt[0] + s_wcnt[1] + s_wcnt[2] + s_wcnt[3];
    if (match) {
        int pfx = __popcll(mask & (((unsigned long long)1 << lane) - 1ull));
        s_list[base + pfx] = tid;   // ascending target order preserved
    }
    __syncthreads();

    const int a = chunk * 256 + tid;
    float cnt = 0.f, boxs = 0.f;
    if (a < A) {
        const float* rp = regp + (b * 4) * A + a;
        float rx = rp[0], ry = rp[A], rw = rp[2 * A], rh = rp[3 * A];
        float gx = (float)(a % H), gy = (float)(a / H);
        float x = (1.f / (1.f + expf(-rx)) + gx) * stride;
        float y = (1.f / (1.f + expf(-ry)) + gy) * stride;
        float w = expf(rw) * stride;
        float h = expf(rh) * stride;
        float px1 = x - 0.5f * w, py1 = y - 0.5f * h;
        float px2 = x + 0.5f * w, py2 = y + 0.5f * h;
        float pw = px2 - px1, ph = py2 - py1;
        float parea = pw * ph;

        float maxiou = -1.f; int best = 0;
        for (int j = 0; j < nT; ++j) {
            int t = s_list[j];
            float ix = fminf(px2, s_x2[t]) - fmaxf(px1, s_x1[t]);
            float iy = fminf(py2, s_y2[t]) - fmaxf(py1, s_y1[t]);
            float inter = fmaxf(ix, 0.f) * fmaxf(iy, 0.f);
            float iou = inter / (parea + s_ar[t] - inter + EPSF);
            if (iou > maxiou) { maxiou = iou; best = t; }
        }
        const bool pos = maxiou > 0.5f;
        btc[sbase + b * A + a] = pos ? s_tc[best] : -1;

        if (pos) {
            cnt = 1.f;
            float gx1 = s_x1[best], gy1 = s_y1[best], gx2 = s_x2[best], gy2 = s_y2[best];
            float gw = gx2 - gx1, gh = gy2 - gy1;
            float ix = fminf(px2, gx2) - fmaxf(px1, gx1);
            float iy = fminf(py2, gy2) - fmaxf(py1, gy1);
            float inter = fmaxf(ix, 0.f) * fmaxf(iy, 0.f);
            float uni = parea + gw * gh - inter + EPSF;
            float iou = inter / uni;
            float cw = fmaxf(px2, gx2) - fminf(px1, gx1);
            float ch = fmaxf(py2, gy2) - fminf(py1, gy1);
            float c2 = cw * cw + ch * ch + EPSF;
            float dx = 0.5f * ((px1 + px2) - (gx1 + gx2));
            float dy = 0.5f * ((py1 + py2) - (gy1 + gy2));
            float rho2 = dx * dx + dy * dy;
            float dv = atanf(gw / (gh + EPSF)) - atanf(pw / (ph + EPSF));
            float v = 0.40528473456935108577f * dv * dv;   // (4/pi^2) dv^2
            float alpha = v / (v - iou + 1.f + EPSF);
            boxs = 1.f - (iou - rho2 / c2 - alpha * v);
        }
    }

    #pragma unroll
    for (int off = 32; off > 0; off >>= 1) {
        cnt  += __shfl_down(cnt,  off, 64);
        boxs += __shfl_down(boxs, off, 64);
    }
    if (lane == 0) { s_red[wave][0] = cnt; s_red[wave][1] = boxs; }
    __syncthreads();
    if (tid == 0) {
        float rc = 0.f, rb = 0.f;
        #pragma unroll
        for (int w = 0; w < 4; ++w) { rc += s_red[w][0]; rb += s_red[w][1]; }
        p1[blockIdx.x] = make_float2(rc, rb);
    }
}

// ---------------- K2: fused cls-BCE + obj over the 43MB class stream ----------------
// Block = 64 consecutive slots of the flat anchor space (blocks never span scales:
// boundaries 102400=1600*64, 128000=2000*64). Wave w owns classes [20w,20w+20);
// lane = (cq, ag): cq = lane>>4 picks a 5-class strip, ag = lane&15 picks 4 anchors.
// 5 independent float4 loads per lane; each cls value read exactly once.
__global__ __launch_bounds__(256)
void yolo_clsobj(const float* __restrict__ cls0, const float* __restrict__ cls1,
                 const float* __restrict__ cls2,
                 const int* __restrict__ btc, float2* __restrict__ p2)
{
    __shared__ float4 s_wmax[4][16];   // [wave][ag] 20-class max for 4 anchors
    __shared__ float  s_cls[4];

    const int tid  = threadIdx.x;
    const int lane = tid & 63, wave = tid >> 6;
    const int cq = lane >> 4, ag = lane & 15;
    const int bid = blockIdx.x;

    const int slot0 = bid * 64 + 4 * ag;
    const float* clsp; int A, b, a;
    if (slot0 < 102400)      { clsp = cls0; A = 6400; b = slot0 / 6400;          a = slot0 - b * 6400; }
    else if (slot0 < 128000) { clsp = cls1; A = 1600; int o = slot0 - 102400; b = o / 1600; a = o - b * 1600; }
    else                     { clsp = cls2; A = 400;  int o = slot0 - 128000; b = o / 400;  a = o - b * 400;  }

    const int cbase = wave * 20 + cq * 5;
    const float* p = clsp + ((size_t)(b * C_NUM + cbase)) * (size_t)A + a;

    // 5 independent 1KB wave-loads
    float4 z0 = *reinterpret_cast<const float4*>(p);
    float4 z1 = *reinterpret_cast<const float4*>(p + (size_t)A);
    float4 z2 = *reinterpret_cast<const float4*>(p + (size_t)2 * A);
    float4 z3 = *reinterpret_cast<const float4*>(p + (size_t)3 * A);
    float4 z4 = *reinterpret_cast<const float4*>(p + (size_t)4 * A);
    int4 t4 = *reinterpret_cast<const int4*>(btc + slot0);

    float4 mx;
    mx.x = fmaxf(fmaxf(fmaxf(z0.x, z1.x), fmaxf(z2.x, z3.x)), z4.x);
    mx.y = fmaxf(fmaxf(fmaxf(z0.y, z1.y), fmaxf(z2.y, z3.y)), z4.y);
    mx.z = fmaxf(fmaxf(fmaxf(z0.z, z1.z), fmaxf(z2.z, z3.z)), z4.z);
    mx.w = fmaxf(fmaxf(fmaxf(z0.w, z1.w), fmaxf(z2.w, z3.w)), z4.w);

    // cls-BCE partial: pos anchors only (rare)
    float sm = 0.f;
    if ((t4.x >= 0) | (t4.y >= 0) | (t4.z >= 0) | (t4.w >= 0)) {
        const float4 zz[5] = { z0, z1, z2, z3, z4 };
        #pragma unroll
        for (int k = 0; k < 5; ++k) {
            const int cg = cbase + k;
            if (t4.x >= 0) { sm += softplusf(zz[k].x); if (cg == t4.x) sm -= zz[k].x; }
            if (t4.y >= 0) { sm += softplusf(zz[k].y); if (cg == t4.y) sm -= zz[k].y; }
            if (t4.z >= 0) { sm += softplusf(zz[k].z); if (cg == t4.z) sm -= zz[k].z; }
            if (t4.w >= 0) { sm += softplusf(zz[k].w); if (cg == t4.w) sm -= zz[k].w; }
        }
    }

    // max across the 4 cq strips (lanes l, l^16, l^32 hold same anchors)
    #pragma unroll
    for (int d = 16; d <= 32; d <<= 1) {
        mx.x = fmaxf(mx.x, __shfl_xor(mx.x, d, 64));
        mx.y = fmaxf(mx.y, __shfl_xor(mx.y, d, 64));
        mx.z = fmaxf(mx.z, __shfl_xor(mx.z, d, 64));
        mx.w = fmaxf(mx.w, __shfl_xor(mx.w, d, 64));
    }
    if (cq == 0) s_wmax[wave][ag] = mx;

    // wave-sum of cls partials
    #pragma unroll
    for (int off = 32; off > 0; off >>= 1) sm += __shfl_down(sm, off, 64);
    if (lane == 0) s_cls[wave] = sm;
    __syncthreads();

    // obj: wave 0 combines the 4 wave-chunk maxes per anchor
    float objp = 0.f;
    if (tid < 64) {
        const float* f0 = reinterpret_cast<const float*>(s_wmax[0]);
        const float* f1 = reinterpret_cast<const float*>(s_wmax[1]);
        const float* f2 = reinterpret_cast<const float*>(s_wmax[2]);
        const float* f3 = reinterpret_cast<const float*>(s_wmax[3]);
        float m = fmaxf(fmaxf(f0[tid], f1[tid]), fmaxf(f2[tid], f3[tid]));
        bool pos = btc[bid * 64 + tid] >= 0;
        objp = softplusf(m) - (pos ? m : 0.f);
        #pragma unroll
        for (int off = 32; off > 0; off >>= 1) objp += __shfl_down(objp, off, 64);
    }
    if (tid == 0) {
        float c = s_cls[0] + s_cls[1] + s_cls[2] + s_cls[3];
        p2[bid] = make_float2(c, objp);
    }
}

// ---------------- K3: final reduction of per-block partials ----------------
__global__ __launch_bounds__(64)
void yolo_finalize(const float2* __restrict__ p1, const float2* __restrict__ p2,
                   float* __restrict__ out)
{
    const int lane = threadIdx.x;
    float np0 = 0.f, np1 = 0.f, np2 = 0.f, bx0 = 0.f, bx1 = 0.f, bx2 = 0.f;
    float cl0 = 0.f, cl1 = 0.f, cl2 = 0.f, ob0 = 0.f, ob1 = 0.f, ob2 = 0.f;

    for (int i = lane; i < 544; i += 64) {
        float2 v = p1[i];
        if (i < 400)      { np0 += v.x; bx0 += v.y; }
        else if (i < 512) { np1 += v.x; bx1 += v.y; }
        else              { np2 += v.x; bx2 += v.y; }
    }
    for (int i = lane; i < 2100; i += 64) {
        float2 v = p2[i];
        if (i < 1600)      { cl0 += v.x; ob0 += v.y; }
        else if (i < 2000) { cl1 += v.x; ob1 += v.y; }
        else               { cl2 += v.x; ob2 += v.y; }
    }
    #pragma unroll
    for (int off = 32; off > 0; off >>= 1) {
        np0 += __shfl_down(np0, off, 64); np1 += __shfl_down(np1, off, 64);
        np2 += __shfl_down(np2, off, 64); bx0 += __shfl_down(bx0, off, 64);
        bx1 += __shfl_down(bx1, off, 64); bx2 += __shfl_down(bx2, off, 64);
        cl0 += __shfl_down(cl0, off, 64); cl1 += __shfl_down(cl1, off, 64);
        cl2 += __shfl_down(cl2, off, 64); ob0 += __shfl_down(ob0, off, 64);
        ob1 += __shfl_down(ob1, off, 64); ob2 += __shfl_down(ob2, off, 64);
    }
    if (lane == 0) {
        float np[3] = { fmaxf(np0, 1.f), fmaxf(np1, 1.f), fmaxf(np2, 1.f) };
        float bx[3] = { bx0, bx1, bx2 };
        float cl[3] = { cl0, cl1, cl2 };
        float ob[3] = { ob0, ob1, ob2 };
        const float inv_anch[3] = { 1.f / (16.f * 6400.f), 1.f / (16.f * 1600.f), 1.f / (16.f * 400.f) };
        float total = 0.f;
        #pragma unroll
        for (int s = 0; s < 3; ++s)
            total += 7.5f * bx[s] / np[s]
                   + 0.5f * cl[s] / (np[s] * (float)C_NUM)
                   + ob[s] * inv_anch[s];
        out[0] = total;
    }
}

extern "C" void kernel_launch(void* const* d_in, const int* in_sizes, int n_in,
                              void* d_out, int out_size, void* d_ws, size_t ws_size,
                              hipStream_t stream) {
    const float *cls[3] = {nullptr, nullptr, nullptr};
    const float *reg[3] = {nullptr, nullptr, nullptr};
    const float *tboxes = nullptr;
    const int *t_batch = nullptr, *t_cls = nullptr;
    for (int i = 0; i < n_in; ++i) {
        switch (in_sizes[i]) {
            case 16 * 80 * 6400: cls[0] = (const float*)d_in[i]; break;
            case 16 * 80 * 1600: cls[1] = (const float*)d_in[i]; break;
            case 16 * 80 * 400:  cls[2] = (const float*)d_in[i]; break;
            case 16 * 4 * 6400:  reg[0] = (const float*)d_in[i]; break;
            case 16 * 4 * 1600:  reg[1] = (const float*)d_in[i]; break;
            case 16 * 4 * 400:   reg[2] = (const float*)d_in[i]; break;
            case 256 * 4:        tboxes = (const float*)d_in[i]; break;
            case 256:
                if (!t_batch) t_batch = (const int*)d_in[i];
                else          t_cls   = (const int*)d_in[i];
                break;
            default: break;
        }
    }
    int*    btc = (int*)d_ws;
    float2* p1  = (float2*)((char*)d_ws + P1_OFF);
    float2* p2  = (float2*)((char*)d_ws + P2_OFF);
    float*  out = (float*)d_out;

    hipLaunchKernelGGL(yolo_match, dim3(544), dim3(256), 0, stream,
                       reg[0], reg[1], reg[2], tboxes, t_batch, t_cls, btc, p1);
    hipLaunchKernelGGL(yolo_clsobj, dim3(2100), dim3(256), 0, stream,
                       cls[0], cls[1], cls[2], btc, p2);
    hipLaunchKernelGGL(yolo_finalize, dim3(1), dim3(64), 0, stream, p1, p2, out);
}